// Round 3
// 628.403 us; speedup vs baseline: 1.0313x; 1.0313x over previous
//
#include <hip/hip_runtime.h>

#define NN 8
#define HH 12
#define DH 64
#define LV 1568
#define LA 512
#define NCV 392
#define NCA 256
#define SCALE 0.125f

#define OUT_STRIDE (LV + LA + 2 * HH * DH + LV + LA)   // 5696
#define OFF_PROB_V 0
#define OFF_PROB_A (LV)                                 // 1568
#define OFF_VCLS   (LV + LA)                            // 2080
#define OFF_ACLS   (LV + LA + HH * DH)                  // 2848
#define OFF_PR_AV  (LV + LA + 2 * HH * DH)              // 3616
#define OFF_PR_VA  (LV + LA + 2 * HH * DH + LV)         // 5184

#define CHA 8   // row-chunks for av rowsum: 256/8 = 32 rows/chunk
#define CHV 8   // row-chunks for va rowsum: 392/8 = 49 rows/chunk

// workspace layout (float offsets) — per-chunk PARTIALS, no atomics, no zero-init
#define WS_RV      0                                     // [CHA][N*H][LV] = 1204224
#define WS_RA      (CHA * NN * HH * LV)                  // [CHV][N*H][LA] = 393216
#define WS_INV_SAV (WS_RA + CHV * NN * HH * LA)
#define WS_INV_SVA (WS_INV_SAV + NN)

// block-range bounds for fused stage-1 kernel
#define B_INV   NN                                       // 8 inv-sum blocks
#define B_CLS   (2 * NN * HH)                            // 192 cls blocks
#define B_RAV   (NN * HH * CHA)                          // 768 av-rowsum blocks
#define B_RVA   (NN * HH * CHV)                          // 768 va-rowsum blocks
#define GRID_S1 (B_INV + B_CLS + B_RAV + B_RVA)          // 1736

// ---------------------------------------------------------------------------
// stage1: inv-sums (blocks 0..7) + cls (8..199) + av-rowsum partials
// (200..967) + va-rowsum partials (968..1735). Small latency-bound blocks
// are dispatched first so they overlap the BW-bound rowsum bulk.
// ---------------------------------------------------------------------------
__global__ __launch_bounds__(256) void stage1_kernel(
        const float* __restrict__ pvq,
        const float* __restrict__ paq,
        const float* __restrict__ av,    // (N,H,LA,LV)
        const float* __restrict__ va,    // (N,H,LV,LA)
        const int* __restrict__ av_ids,
        const int* __restrict__ va_ids,
        const float* __restrict__ n_av,
        const float* __restrict__ n_va,
        float* __restrict__ ws,
        float* __restrict__ out) {
    int b = blockIdx.x;
    int t = threadIdx.x;
    __shared__ float red[4][DH];
    __shared__ float wred[4];
    __shared__ int   sIdx[64];
    __shared__ float sW[64];

    if (b < B_INV) {
        // ---- inverse sums of gathered n_attn ----
        int n = b;
        float vs = 0.f, as = 0.f;
        for (int l = t; l < NCV; l += 256) vs += n_av[n * LV + av_ids[n * LV + l]];
        if (t < NCA) as = n_va[n * LA + va_ids[n * LA + t]];
        for (int m = 32; m; m >>= 1) { vs += __shfl_xor(vs, m); as += __shfl_xor(as, m); }
        int wave = t >> 6;
        if ((t & 63) == 0) { red[wave][0] = vs; wred[wave] = as; }
        __syncthreads();
        if (t == 0) {
            float S0 = red[0][0] + red[1][0] + red[2][0] + red[3][0];
            float S1 = wred[0] + wred[1] + wred[2] + wred[3];
            ws[WS_INV_SAV + n] = 1.f / S0;
            ws[WS_INV_SVA + n] = 1.f / S1;
        }
        return;
    }
    b -= B_INV;

    if (b < B_CLS) {
        // ---- class tokens ----
        int wave = t >> 6, lane = t & 63;
        if (b < NN * HH) {
            int n = b / HH, h = b % HH;
            float acc = 0.f, wsum = 0.f;
            for (int l = wave; l < NCV; l += 4) {
                int ridx = av_ids[n * LV + l];
                float w  = n_av[n * LV + ridx];
                acc  += pvq[((size_t)b * LV + ridx) * DH + lane] * w;
                wsum += w;
            }
            red[wave][lane] = acc;
            if (lane == 0) wred[wave] = wsum;
            __syncthreads();
            if (wave == 0) {
                float s = red[0][lane] + red[1][lane] + red[2][lane] + red[3][lane];
                float W = wred[0] + wred[1] + wred[2] + wred[3];
                out[(size_t)n * OUT_STRIDE + OFF_VCLS + h * DH + lane] = s / W;
            }
        } else {
            int b2 = b - NN * HH;
            int n = b2 / HH, h = b2 % HH;
            float acc = 0.f, wsum = 0.f;
            for (int l = wave; l < NCA; l += 4) {
                int ridx = va_ids[n * LA + l];
                float w  = n_va[n * LA + ridx];
                acc  += paq[((size_t)b2 * LA + ridx) * DH + lane] * w;
                wsum += w;
            }
            red[wave][lane] = acc;
            if (lane == 0) wred[wave] = wsum;
            __syncthreads();
            if (wave == 0) {
                float s = red[0][lane] + red[1][lane] + red[2][lane] + red[3][lane];
                float W = wred[0] + wred[1] + wred[2] + wred[3];
                out[(size_t)n * OUT_STRIDE + OFF_ACLS + h * DH + lane] = s / W;
            }
        }
        return;
    }
    b -= B_CLS;

    if (b < B_RAV) {
        // ---- av rowsum partial: Rv_p[chunk][nh][c] = sum over 32 selected rows ----
        int chunk = b % CHA;
        int nh    = b / CHA;
        int n     = nh / HH;
        const int rows = NCA / CHA;        // 32
        if (t < rows) {
            int ridx = va_ids[n * LA + chunk * rows + t];
            sIdx[t] = ridx;
            sW[t]   = n_va[n * LA + ridx];
        }
        __syncthreads();
        float4 acc0 = {0.f, 0.f, 0.f, 0.f};
        float4 acc1 = {0.f, 0.f, 0.f, 0.f};
        const int c0 = t;                  // float4 column
        const int c1 = t + 256;
        const bool has1 = (c1 < LV / 4);   // LV/4 = 392
        #pragma unroll 4
        for (int r = 0; r < rows; ++r) {
            float w = sW[r];
            const float4* row = (const float4*)(av + ((size_t)nh * LA + sIdx[r]) * LV);
            float4 x0 = row[c0];
            acc0.x += x0.x * w; acc0.y += x0.y * w; acc0.z += x0.z * w; acc0.w += x0.w * w;
            if (has1) {
                float4 x1 = row[c1];
                acc1.x += x1.x * w; acc1.y += x1.y * w; acc1.z += x1.z * w; acc1.w += x1.w * w;
            }
        }
        float4* outp = (float4*)(ws + WS_RV + ((size_t)chunk * NN * HH + nh) * LV);
        outp[c0] = acc0;
        if (has1) outp[c1] = acc1;
        return;
    }
    b -= B_RAV;

    {
        // ---- va rowsum partial: Ra_p[chunk][nh][c] = sum over 49 selected rows ----
        int chunk = b % CHV;
        int nh    = b / CHV;
        int n     = nh / HH;
        const int rows = NCV / CHV;        // 49
        if (t < rows) {
            int ridx = av_ids[n * LV + chunk * rows + t];
            sIdx[t] = ridx;
            sW[t]   = n_av[n * LV + ridx];
        }
        __syncthreads();
        float2 acc = {0.f, 0.f};
        #pragma unroll 4
        for (int r = 0; r < rows; ++r) {
            float w = sW[r];
            const float2* row = (const float2*)(va + ((size_t)nh * LV + sIdx[r]) * LA);
            float2 x = row[t];             // LA/2 = 256 exactly
            acc.x += x.x * w; acc.y += x.y * w;
        }
        ((float2*)(ws + WS_RA + ((size_t)chunk * NN * HH + nh) * LA))[t] = acc;
    }
}

// ---------------------------------------------------------------------------
// prob: main region = one wave per (n, selected token l<NC): 12 head-dots
// via butterfly, fold the 8 rowsum partials (L2-hit uniform loads), sigmoid
// mean, scattered prob+prune write from lane 0.
// tail region = one THREAD per (n, token l>=NC): prob 0, prune passthrough.
// ---------------------------------------------------------------------------
#define MAIN_W  (NN * NCV + NN * NCA)                    // 5184 waves
#define MAIN_B  (MAIN_W / 4)                             // 1296 blocks
#define TAILV   (NN * (LV - NCV))                        // 9408
#define TAILA   (NN * (LA - NCA))                        // 2048
#define TAIL_B  ((TAILV + TAILA + 255) / 256)            // 45 blocks
#define GRID_PB (MAIN_B + TAIL_B)                        // 1341

__global__ __launch_bounds__(256) void prob_kernel(
        const float* __restrict__ pvk,
        const float* __restrict__ pak,
        const float* __restrict__ spu_a,   // (N,H,DH)
        const float* __restrict__ spu_v,
        const int* __restrict__ av_ids,
        const int* __restrict__ va_ids,
        const float* __restrict__ n_av,
        const float* __restrict__ n_va,
        const float* __restrict__ u_v,
        const float* __restrict__ u_a,
        const float* __restrict__ ws,
        float* __restrict__ out) {
    if (blockIdx.x < MAIN_B) {
        int W = blockIdx.x * 4 + (threadIdx.x >> 6);
        int lane = threadIdx.x & 63;
        if (W < NN * NCV) {
            int n = W / NCV, l = W % NCV;
            int col = av_ids[n * LV + l];
            float invS = ws[WS_INV_SVA + n];
            float psum = 0.f;
            #pragma unroll
            for (int h = 0; h < HH; ++h) {
                int nh = n * HH + h;
                float prod = pvk[((size_t)nh * LV + col) * DH + lane] * spu_a[nh * DH + lane];
                for (int m = 32; m; m >>= 1) prod += __shfl_xor(prod, m);
                float pos = 0.f;
                #pragma unroll
                for (int p = 0; p < CHA; ++p)
                    pos += ws[WS_RV + ((size_t)p * NN * HH + nh) * LV + col];
                psum += 1.f / (1.f + __expf(pos * invS - prod * SCALE));
            }
            float pm = psum * (1.f / HH);
            if (lane == 0) {
                out[(size_t)n * OUT_STRIDE + OFF_PROB_V + col] = pm;
                float uv = u_v[n * LV + col];
                out[(size_t)n * OUT_STRIDE + OFF_PR_AV + col] =
                    (uv < pm) ? 0.f : n_av[n * LV + col];
            }
        } else {
            int W2 = W - NN * NCV;
            int n = W2 / NCA, l = W2 % NCA;
            int col = va_ids[n * LA + l];
            float invS = ws[WS_INV_SAV + n];
            float psum = 0.f;
            #pragma unroll
            for (int h = 0; h < HH; ++h) {
                int nh = n * HH + h;
                float prod = pak[((size_t)nh * LA + col) * DH + lane] * spu_v[nh * DH + lane];
                for (int m = 32; m; m >>= 1) prod += __shfl_xor(prod, m);
                float pos = 0.f;
                #pragma unroll
                for (int p = 0; p < CHV; ++p)
                    pos += ws[WS_RA + ((size_t)p * NN * HH + nh) * LA + col];
                psum += 1.f / (1.f + __expf(pos * invS - prod * SCALE));
            }
            float pm = psum * (1.f / HH);
            if (lane == 0) {
                out[(size_t)n * OUT_STRIDE + OFF_PROB_A + col] = pm;
                float ua = u_a[n * LA + col];
                out[(size_t)n * OUT_STRIDE + OFF_PR_VA + col] =
                    (ua < pm) ? 0.f : n_va[n * LA + col];
            }
        }
    } else {
        // dense tail: prob = 0, so (u < 0) is always false -> prune = n_attn
        int tid = (blockIdx.x - MAIN_B) * 256 + threadIdx.x;
        if (tid < TAILV) {
            int n = tid / (LV - NCV), l = NCV + tid % (LV - NCV);
            int col = av_ids[n * LV + l];
            out[(size_t)n * OUT_STRIDE + OFF_PROB_V + col] = 0.f;
            out[(size_t)n * OUT_STRIDE + OFF_PR_AV + col] = n_av[n * LV + col];
        } else if (tid < TAILV + TAILA) {
            int i = tid - TAILV;
            int n = i / (LA - NCA), l = NCA + i % (LA - NCA);
            int col = va_ids[n * LA + l];
            out[(size_t)n * OUT_STRIDE + OFF_PROB_A + col] = 0.f;
            out[(size_t)n * OUT_STRIDE + OFF_PR_VA + col] = n_va[n * LA + col];
        }
    }
}

extern "C" void kernel_launch(void* const* d_in, const int* in_sizes, int n_in,
                              void* d_out, int out_size, void* d_ws, size_t ws_size,
                              hipStream_t stream) {
    const float* pvq   = (const float*)d_in[0];
    const float* pvk   = (const float*)d_in[1];
    const float* paq   = (const float*)d_in[2];
    const float* pak   = (const float*)d_in[3];
    const float* av    = (const float*)d_in[4];
    const float* va    = (const float*)d_in[5];
    const float* n_av  = (const float*)d_in[6];
    const float* n_va  = (const float*)d_in[7];
    const float* spu_a = (const float*)d_in[8];
    const float* spu_v = (const float*)d_in[9];
    const float* u_v   = (const float*)d_in[10];
    const float* u_a   = (const float*)d_in[11];
    const int* av_ids  = (const int*)d_in[12];
    const int* va_ids  = (const int*)d_in[13];
    float* out = (float*)d_out;
    float* ws  = (float*)d_ws;

    stage1_kernel<<<GRID_S1, 256, 0, stream>>>(pvq, paq, av, va, av_ids, va_ids,
                                               n_av, n_va, ws, out);
    prob_kernel<<<GRID_PB, 256, 0, stream>>>(pvk, pak, spu_a, spu_v,
                                             av_ids, va_ids, n_av, n_va,
                                             u_v, u_a, ws, out);
}